// Round 5
// baseline (266.496 us; speedup 1.0000x reference)
//
#include <hip/hip_runtime.h>

// Multi-head causal attention fwd, B=2 S=2048 D=1024 H=16 DK=DV=64.
// fp32 I/O; internal bf16 MFMA pipeline.
// attn: LDS-free, barrier-free, 32x32x16 MFMA, per-lane softmax (S^T form),
// in-register P^T construction via cross-half shuffles, O^T accumulation.

typedef __bf16 bf16;
typedef __bf16 bf16x2 __attribute__((ext_vector_type(2)));
typedef __bf16 bf16x4 __attribute__((ext_vector_type(4)));
typedef __bf16 bf16x8 __attribute__((ext_vector_type(8)));
typedef float  f32x4  __attribute__((ext_vector_type(4)));
typedef float  f32x16 __attribute__((ext_vector_type(16)));

#define B_  2
#define S_  2048
#define D_  1024
#define H_  16
#define HD  64
#define NEG_BIG (-3.0e38f)
#define SCALE_LOG2E 0.1803368801111204f   // (1/8) * log2(e)

__device__ __forceinline__ void lds16(const void* g, void* l) {
    __builtin_amdgcn_global_load_lds((const __attribute__((address_space(1))) void*)g,
                                     (__attribute__((address_space(3))) void*)l, 16, 0, 0);
}

__device__ __forceinline__ f32x4 mfma16(bf16x8 a, bf16x8 b, f32x4 c) {
    return __builtin_amdgcn_mfma_f32_16x16x32_bf16(a, b, c, 0, 0, 0);
}
__device__ __forceinline__ f32x16 mfma32(bf16x8 a, bf16x8 b, f32x16 c) {
    return __builtin_amdgcn_mfma_f32_32x32x16_bf16(a, b, c, 0, 0, 0);
}
__device__ __forceinline__ int pk2(float a, float b) {
    union { bf16x2 h; int i; } u;
    u.h[0] = (bf16)a; u.h[1] = (bf16)b;
    return u.i;
}

// ---------------- fp32 -> bf16 convert pre-pass ----------------
__global__ __launch_bounds__(256) void convert_k(const float* __restrict__ X,
                                                 const float* __restrict__ wq,
                                                 const float* __restrict__ wk,
                                                 const float* __restrict__ wv,
                                                 const float* __restrict__ wo,
                                                 bf16* __restrict__ dst) {
    const int gid = blockIdx.x * 256 + threadIdx.x;
    const int i   = gid * 4;
    const float* src;
    int off;
    if      (i < (4 << 20)) { src = X;  off = 0; }
    else if (i < (5 << 20)) { src = wq; off = 4 << 20; }
    else if (i < (6 << 20)) { src = wk; off = 5 << 20; }
    else if (i < (7 << 20)) { src = wv; off = 6 << 20; }
    else                    { src = wo; off = 7 << 20; }
    const float4 v = *(const float4*)(src + (i - off));
    bf16x4 p;
    p[0] = (bf16)v.x; p[1] = (bf16)v.y; p[2] = (bf16)v.z; p[3] = (bf16)v.w;
    *(bf16x4*)(dst + i) = p;
}

// ---------------- fused QKV GEMM (unchanged, 768 blocks = 3/CU) ----------------
__global__ __launch_bounds__(256) void gemm_qkv(const bf16* __restrict__ A,
                                                const bf16* __restrict__ Wq,
                                                const bf16* __restrict__ Wk,
                                                const bf16* __restrict__ Wv,
                                                const float* __restrict__ bq,
                                                const float* __restrict__ bk,
                                                const float* __restrict__ bv,
                                                bf16* __restrict__ Qw,
                                                bf16* __restrict__ Kw,
                                                bf16* __restrict__ Vw) {
    constexpr int K = 1024;
    __shared__ bf16 sA[128 * 32];
    __shared__ bf16 sB[128 * 32];
    const int tid  = threadIdx.x;
    const int l15  = tid & 15;
    const int quad = (tid & 63) >> 4;
    const int wid  = tid >> 6;
    const int seg  = blockIdx.x >> 3;
    const int bn   = blockIdx.x & 7;
    const int bm   = blockIdx.y;
    const int wm   = (wid >> 1) * 64;
    const int wn   = (wid & 1) * 64;

    const bf16* W    = (seg == 0) ? Wq : (seg == 1) ? Wk : Wv;
    const float* bias = (seg == 0) ? bq : (seg == 1) ? bk : bv;

    const bf16* Ab = A + (size_t)bm * 128 * K;
    const bf16* Wb = W + (size_t)bn * 128 * K;

    f32x4 acc[4][4] = {};

    for (int k0 = 0; k0 < K; k0 += 32) {
        __syncthreads();
        #pragma unroll
        for (int it = 0; it < 2; ++it) {
            int c = it * 256 + tid;
            int row = c >> 2, c8 = c & 3;
            lds16(Ab + row * K + k0 + c8 * 8, (char*)sA + c * 16);
            lds16(Wb + row * K + k0 + c8 * 8, (char*)sB + c * 16);
        }
        __syncthreads();
        bf16x8 af[4], bfr[4];
        #pragma unroll
        for (int i = 0; i < 4; ++i)
            af[i] = *(const bf16x8*)&sA[(wm + i * 16 + l15) * 32 + quad * 8];
        #pragma unroll
        for (int i = 0; i < 4; ++i)
            bfr[i] = *(const bf16x8*)&sB[(wn + i * 16 + l15) * 32 + quad * 8];
        #pragma unroll
        for (int mi = 0; mi < 4; ++mi)
            #pragma unroll
            for (int ni = 0; ni < 4; ++ni)
                acc[mi][ni] = mfma16(af[mi], bfr[ni], acc[mi][ni]);
    }

    #pragma unroll
    for (int ni = 0; ni < 4; ++ni) {
        const int n  = bn * 128 + wn + ni * 16 + l15;
        const float bv_ = bias[n];
        const int h = n >> 6;
        #pragma unroll
        for (int mi = 0; mi < 4; ++mi) {
            const int m0 = bm * 128 + wm + mi * 16 + quad * 4;
            if (seg == 2) {   // V transposed: [B,H,64,S]
                const int dv = n & 63;
                const int b = m0 >> 11, s = m0 & 2047;
                bf16x4 pack;
                #pragma unroll
                for (int r = 0; r < 4; ++r) pack[r] = (bf16)(acc[mi][ni][r] + bv_);
                *(bf16x4*)&Vw[(((size_t)(b * H_ + h) * HD + dv) << 11) + s] = pack;
            } else {          // Q,K: [B,H,S,64]
                bf16* C = (seg == 0) ? Qw : Kw;
                const int dk = n & 63;
                #pragma unroll
                for (int r = 0; r < 4; ++r) {
                    const int m = m0 + r, b = m >> 11, s = m & 2047;
                    C[(((size_t)(b * H_ + h) << 11) + s) * HD + dk] =
                        (bf16)(acc[mi][ni][r] + bv_);
                }
            }
        }
    }
}

// ---------------- final GEMM: out fp32 = A @ Wo^T + bias ----------------
// M-tile 64 -> 512 blocks (2/CU) for occupancy.
__global__ __launch_bounds__(256) void gemm_fin(const bf16* __restrict__ A,
                                                const bf16* __restrict__ W,
                                                const float* __restrict__ bias,
                                                float* __restrict__ C) {
    constexpr int N = 1024, K = 1024;
    __shared__ bf16 sA[64 * 32];
    __shared__ bf16 sB[128 * 32];
    const int tid  = threadIdx.x;
    const int l15  = tid & 15;
    const int quad = (tid & 63) >> 4;
    const int wid  = tid >> 6;
    const int bm   = blockIdx.x >> 3;    // 64 m-tiles of 64 rows
    const int bn   = blockIdx.x & 7;
    const int wm   = (wid & 1) * 32;
    const int wn   = (wid >> 1) * 64;

    const bf16* Ab = A + (size_t)bm * 64 * K;
    const bf16* Wb = W + (size_t)bn * 128 * K;

    f32x4 acc[2][4] = {};

    for (int k0 = 0; k0 < K; k0 += 32) {
        __syncthreads();
        {   // A-tile: 64 rows x 64B = 256 16B-chunks
            int c = tid, row = c >> 2, c8 = c & 3;
            lds16(Ab + row * K + k0 + c8 * 8, (char*)sA + c * 16);
        }
        #pragma unroll
        for (int it = 0; it < 2; ++it) {
            int c = it * 256 + tid;
            int row = c >> 2, c8 = c & 3;
            lds16(Wb + row * K + k0 + c8 * 8, (char*)sB + c * 16);
        }
        __syncthreads();
        bf16x8 af[2], bfr[4];
        #pragma unroll
        for (int i = 0; i < 2; ++i)
            af[i] = *(const bf16x8*)&sA[(wm + i * 16 + l15) * 32 + quad * 8];
        #pragma unroll
        for (int i = 0; i < 4; ++i)
            bfr[i] = *(const bf16x8*)&sB[(wn + i * 16 + l15) * 32 + quad * 8];
        #pragma unroll
        for (int mi = 0; mi < 2; ++mi)
            #pragma unroll
            for (int ni = 0; ni < 4; ++ni)
                acc[mi][ni] = mfma16(af[mi], bfr[ni], acc[mi][ni]);
    }

    #pragma unroll
    for (int ni = 0; ni < 4; ++ni) {
        const int n  = bn * 128 + wn + ni * 16 + l15;
        const float bv = bias[n];
        #pragma unroll
        for (int mi = 0; mi < 2; ++mi) {
            const int m0 = bm * 64 + wm + mi * 16 + quad * 4;
            #pragma unroll
            for (int r = 0; r < 4; ++r)
                C[(size_t)(m0 + r) * N + n] = acc[mi][ni][r] + bv;
        }
    }
}

// ---------------- Flash attention: LDS-free, barrier-free ----------------
// Wave = 32-q strip. S^T = K*Q^T via 32x32x16 (C col = q = lane&31).
// Per-lane online softmax (1 shfl_xor(32) per reduction).
// O^T = V^T * P^T (O col = q too -> scalar alpha rescale).
// P^T B-frags built in-register: pack pairs + shfl_xor(32).
// Frags load straight from global (L2-hot); K prefetched one group ahead.
template <int NS>
__device__ __forceinline__ void attn_group(
    int sub0, int s, int l31, int hi,
    const bf16* __restrict__ Kg, const bf16* __restrict__ Vg,
    const float* __restrict__ pmg,
    const bf16x8 (&qf)[4], bf16x8 (&kf)[2][4],
    float& m_i, float& l_i, f32x16 (&ot)[2], int nsubT)
{
    // S^T = K * Q^T
    f32x16 st[NS] = {};
    #pragma unroll
    for (int su = 0; su < NS; ++su)
        #pragma unroll
        for (int ks = 0; ks < 4; ++ks)
            st[su] = mfma32(kf[su][ks], qf[ks], st[su]);

    // V^T A-frags for this group (latency hidden under softmax below)
    bf16x8 vf[2][NS][2];
    #pragma unroll
    for (int t = 0; t < 2; ++t)
        #pragma unroll
        for (int su = 0; su < NS; ++su)
            #pragma unroll
            for (int k2 = 0; k2 < 2; ++k2)
                vf[t][su][k2] = *(const bf16x8*)
                    (Vg + (size_t)(t * 32 + l31) * S_ + (sub0 + su) * 32 + k2 * 16 + hi * 8);

    // padding-mask vectors
    float4 pmv[NS][4];
    #pragma unroll
    for (int su = 0; su < NS; ++su)
        #pragma unroll
        for (int rg = 0; rg < 4; ++rg)
            pmv[su][rg] = *(const float4*)(pmg + (sub0 + su) * 32 + rg * 8 + hi * 4);

    // prefetch next group's K frags (consumed next call; hidden under softmax+PV)
    {
        const int nxt = sub0 + NS;
        const int nrem = nsubT - nxt;
        if (nrem > 0) {
            #pragma unroll
            for (int ks = 0; ks < 4; ++ks)
                kf[0][ks] = *(const bf16x8*)
                    (Kg + (size_t)(nxt * 32 + l31) * HD + ks * 16 + hi * 8);
            if (nrem > 1)
                #pragma unroll
                for (int ks = 0; ks < 4; ++ks)
                    kf[1][ks] = *(const bf16x8*)
                        (Kg + (size_t)((nxt + 1) * 32 + l31) * HD + ks * 16 + hi * 8);
        }
    }

    // scale + padding + causal (diag only on last sub of last group)
    float sv[NS][16];
    const int thr = l31 - 4 * hi;
    #pragma unroll
    for (int su = 0; su < NS; ++su) {
        const bool dg = (sub0 + su == s);
        #pragma unroll
        for (int rg = 0; rg < 4; ++rg) {
            const float4 pf = pmv[su][rg];
            #pragma unroll
            for (int e = 0; e < 4; ++e) {
                const int r = rg * 4 + e;
                float v = st[su][r] * SCALE_LOG2E;
                if (((const float*)&pf)[e] > 0.f) v = NEG_BIG;
                if (dg && (e + 8 * rg > thr)) v = NEG_BIG;
                sv[su][r] = v;
            }
        }
    }

    // per-lane online softmax (lane holds NS*16 keys of its q)
    float rm = sv[0][0];
    #pragma unroll
    for (int su = 0; su < NS; ++su)
        #pragma unroll
        for (int r = 0; r < 16; ++r) rm = fmaxf(rm, sv[su][r]);
    rm = fmaxf(rm, __shfl_xor(rm, 32));
    const float mn    = fmaxf(m_i, rm);
    const float alpha = exp2f(m_i - mn);
    m_i = mn;
    float rs = 0.f;
    #pragma unroll
    for (int su = 0; su < NS; ++su)
        #pragma unroll
        for (int r = 0; r < 16; ++r) {
            const float p = exp2f(sv[su][r] - mn);
            sv[su][r] = p;
            rs += p;
        }
    rs += __shfl_xor(rs, 32);
    l_i = l_i * alpha + rs;
    ot[0] *= alpha;
    ot[1] *= alpha;

    // P^T B-frags via packed cross-half shuffles, then O^T += V^T * P^T
    #pragma unroll
    for (int su = 0; su < NS; ++su) {
        int P[8], X[8];
        #pragma unroll
        for (int i = 0; i < 8; ++i) {
            P[i] = pk2(sv[su][2 * i], sv[su][2 * i + 1]);
            X[i] = __shfl_xor(P[i], 32);
        }
        union { int d[4]; bf16x8 v; } f0, f1;
        if (hi == 0) {
            f0.d[0] = P[0]; f0.d[1] = P[1]; f0.d[2] = X[0]; f0.d[3] = X[1];
            f1.d[0] = P[4]; f1.d[1] = P[5]; f1.d[2] = X[4]; f1.d[3] = X[5];
        } else {
            f0.d[0] = X[2]; f0.d[1] = X[3]; f0.d[2] = P[2]; f0.d[3] = P[3];
            f1.d[0] = X[6]; f1.d[1] = X[7]; f1.d[2] = P[6]; f1.d[3] = P[7];
        }
        #pragma unroll
        for (int t = 0; t < 2; ++t) {
            ot[t] = mfma32(vf[t][su][0], f0.v, ot[t]);
            ot[t] = mfma32(vf[t][su][1], f1.v, ot[t]);
        }
    }
}

__global__ __launch_bounds__(256, 2) void attn_k(const bf16* __restrict__ Q,
                                                 const bf16* __restrict__ K,
                                                 const bf16* __restrict__ Vt,
                                                 const float* __restrict__ pmask,
                                                 bf16* __restrict__ Aout) {
    const int lane = threadIdx.x & 63;
    const int l31  = lane & 31;
    const int hi   = lane >> 5;
    const int wid  = threadIdx.x >> 6;
    const int jj   = blockIdx.x >> 5;     // 0..15
    const int bh   = blockIdx.x & 31;
    const int b    = bh >> 4;
    const int h    = bh & 15;
    // longest-first strip pairing: block sums to a constant 130 sub-tiles
    const int s = (wid < 2) ? (2 * jj + wid)
                            : ((wid == 2) ? (62 - 2 * jj) : (63 - 2 * jj));
    const int nsubT = s + 1;              // # 32-key sub-tiles (exact causal)

    const bf16* Qg = Q  + ((size_t)bh * S_ + s * 32) * HD;
    const bf16* Kg = K  + (size_t)bh * S_ * HD;
    const bf16* Vg = Vt + (size_t)bh * HD * S_;
    const float* pmg = pmask + b * S_;

    // Q B-frags (cached whole kernel): B[k][n=q]: n=l31, k=ks*16+hi*8+j
    bf16x8 qf[4];
    #pragma unroll
    for (int ks = 0; ks < 4; ++ks)
        qf[ks] = *(const bf16x8*)(Qg + l31 * HD + ks * 16 + hi * 8);

    // preload first group's K A-frags: A[m=key]: m=l31, k=ks*16+hi*8+j
    bf16x8 kf[2][4];
    {
        const int n0 = (nsubT < 2) ? nsubT : 2;
        for (int su = 0; su < n0; ++su)
            #pragma unroll
            for (int ks = 0; ks < 4; ++ks)
                kf[su][ks] = *(const bf16x8*)
                    (Kg + (size_t)(su * 32 + l31) * HD + ks * 16 + hi * 8);
    }

    float m_i = NEG_BIG, l_i = 0.f;
    f32x16 ot[2] = {};

    const int full = nsubT >> 1;
    for (int g = 0; g < full; ++g)
        attn_group<2>(g * 2, s, l31, hi, Kg, Vg, pmg, qf, kf, m_i, l_i, ot, nsubT);
    if (nsubT & 1)
        attn_group<1>(nsubT - 1, s, l31, hi, Kg, Vg, pmg, qf, kf, m_i, l_i, ot, nsubT);

    // epilogue: O^T rows dv = rg*8+hi*4+e, col q = l31
    const float inv = 1.f / l_i;
    const int q = s * 32 + l31;
    bf16* outp = Aout + ((size_t)b * S_ + q) * D_ + h * HD;
    #pragma unroll
    for (int t = 0; t < 2; ++t)
        #pragma unroll
        for (int rg = 0; rg < 4; ++rg) {
            bf16x4 pv;
            #pragma unroll
            for (int e = 0; e < 4; ++e) pv[e] = (bf16)(ot[t][rg * 4 + e] * inv);
            *(bf16x4*)(outp + t * 32 + rg * 8 + hi * 4) = pv;
        }
}

extern "C" void kernel_launch(void* const* d_in, const int* in_sizes, int n_in,
                              void* d_out, int out_size, void* d_ws, size_t ws_size,
                              hipStream_t stream) {
    const float* X   = (const float*)d_in[0];
    const float* pm  = (const float*)d_in[1];
    const float* wq  = (const float*)d_in[2];
    const float* bq  = (const float*)d_in[3];
    const float* wk  = (const float*)d_in[4];
    const float* bk  = (const float*)d_in[5];
    const float* wv  = (const float*)d_in[6];
    const float* bvb = (const float*)d_in[7];
    const float* wo  = (const float*)d_in[8];
    const float* bo  = (const float*)d_in[9];
    float* out = (float*)d_out;

    char* ws = (char*)d_ws;
    bf16* Xb  = (bf16*)(ws);                  // 4M elems  8 MiB
    bf16* Wqb = (bf16*)(ws + (8u  << 20));    // 1M elems  2 MiB each
    bf16* Wkb = (bf16*)(ws + (10u << 20));
    bf16* Wvb = (bf16*)(ws + (12u << 20));
    bf16* Wob = (bf16*)(ws + (14u << 20));
    bf16* Qw  = (bf16*)(ws + (16u << 20));    // [B,H,S,64]  8 MiB
    bf16* Kw  = (bf16*)(ws + (24u << 20));    // [B,H,S,64]  8 MiB
    bf16* Vw  = (bf16*)(ws + (32u << 20));    // [B,H,64,S]  8 MiB
    bf16* Aw  = (bf16*)(ws + (40u << 20));    // [B*S, 1024] 8 MiB

    convert_k<<<dim3(8192), dim3(256), 0, stream>>>(X, wq, wk, wv, wo, Xb);
    gemm_qkv<<<dim3(24, 32), dim3(256), 0, stream>>>(Xb, Wqb, Wkb, Wvb,
                                                     bq, bk, bvb, Qw, Kw, Vw);
    attn_k<<<dim3(512), dim3(256), 0, stream>>>(Qw, Kw, Vw, pm, Aw);
    gemm_fin<<<dim3(512), dim3(256), 0, stream>>>(Aw, Wob, bo, out);
}